// Round 5
// baseline (150.579 us; speedup 1.0000x reference)
//
#include <hip/hip_runtime.h>

#define DIN 256
#define DHID 256
#define DEDGE 64
#define W2_PAD 264  // bf16 row stride in LDS: 528 B, breaks bank aliasing

typedef float f32x4 __attribute__((ext_vector_type(4)));
typedef short s16x8 __attribute__((ext_vector_type(8)));
typedef unsigned short u16x8 __attribute__((ext_vector_type(8)));

__device__ __forceinline__ unsigned short f2bf(float f) {
    unsigned int u = __builtin_bit_cast(unsigned int, f);
    u += 0x7fffu + ((u >> 16) & 1u);   // RNE (values finite here)
    return (unsigned short)(u >> 16);
}

// -------- Kernel 1: h[r][c] = x[r,:] . W_in[c,:] + b_in[c] ------------------
__global__ __launch_bounds__(256) void k_h(
    const float* __restrict__ x, const float* __restrict__ Win,
    const float* __restrict__ bin, float* __restrict__ h)
{
    __shared__ float xs[4][DIN];
    const int r0 = blockIdx.x * 4;
    const int tid = threadIdx.x;
#pragma unroll
    for (int rr = 0; rr < 4; ++rr)
        xs[rr][tid] = x[(r0 + rr) * DIN + tid];
    __syncthreads();

    float acc[4] = {0.f, 0.f, 0.f, 0.f};
    const float* wrow = Win + tid * DIN;
    for (int d = 0; d < DIN; d += 8) {
        const f32x4 w0 = *reinterpret_cast<const f32x4*>(wrow + d);
        const f32x4 w1 = *reinterpret_cast<const f32x4*>(wrow + d + 4);
#pragma unroll
        for (int q = 0; q < 4; ++q) {
#pragma unroll
            for (int rr = 0; rr < 4; ++rr) {
                acc[rr] += xs[rr][d + q] * w0[q];
                acc[rr] += xs[rr][d + 4 + q] * w1[q];
            }
        }
    }
    const float bias = bin[tid];
#pragma unroll
    for (int rr = 0; rr < 4; ++rr)
        h[(r0 + rr) * DHID + tid] = acc[rr] + bias;
}

// -------- Kernel 2: pa = h@Wa^T, pb = h@Wb^T (fp32, no bias) ----------------
__global__ __launch_bounds__(256) void k_pab(
    const float* __restrict__ h, const float* __restrict__ W1,
    float* __restrict__ pa, float* __restrict__ pb)
{
    __shared__ float hs[4][DHID];
    const int r0 = blockIdx.x * 4;
    const int tid = threadIdx.x;
#pragma unroll
    for (int rr = 0; rr < 4; ++rr)
        hs[rr][tid] = h[(r0 + rr) * DHID + tid];
    __syncthreads();

    float accA[4] = {0.f, 0.f, 0.f, 0.f};
    float accB[4] = {0.f, 0.f, 0.f, 0.f};
    const float* w1row = W1 + tid * (2 * DHID);
    for (int d = 0; d < DHID; d += 4) {
        const f32x4 wa = *reinterpret_cast<const f32x4*>(w1row + d);
        const f32x4 wb = *reinterpret_cast<const f32x4*>(w1row + DHID + d);
#pragma unroll
        for (int q = 0; q < 4; ++q) {
#pragma unroll
            for (int rr = 0; rr < 4; ++rr) {
                accA[rr] += hs[rr][d + q] * wa[q];
                accB[rr] += hs[rr][d + q] * wb[q];
            }
        }
    }
#pragma unroll
    for (int rr = 0; rr < 4; ++rr) {
        pa[(r0 + rr) * DHID + tid] = accA[rr];
        pb[(r0 + rr) * DHID + tid] = accB[rr];
    }
}

// -------- Kernel 3: fused z=silu(pa_i+pb_j+b1); out = z@W2^T + b2 (MFMA) ----
// grid (jb=4, i=256, b=4), 256 thr = 4 waves; wave: 16 j-rows x 64 e-cols.
// A[m=lane&15][k=quad*8+reg] (m->j), B[k][n=lane&15] (n->e),
// C/D: col(n)=lane&15, row(m)=quad*4+reg.   (cross-validated vs VALU in R3)
// OUTPUT IS FP32 (reference returns float32; harness stores output dtype).
__global__ __launch_bounds__(256, 4) void k_out(
    const float* __restrict__ pa, const float* __restrict__ pb,
    const float* __restrict__ b1, const float* __restrict__ W2,
    const float* __restrict__ b2, float* __restrict__ out)
{
    __shared__ unsigned short w2s[DEDGE * W2_PAD];
    __shared__ float pab1[DHID];

    const int jb = blockIdx.x, i = blockIdx.y, b = blockIdx.z;
    const int tid = threadIdx.x;

    pab1[tid] = pa[(((b << 8) + i) << 8) + tid] + b1[tid];
#pragma unroll
    for (int it = 0; it < 8; ++it) {
        const int t = tid + it * 256;
        const int row = t >> 5;
        const int cc = (t & 31) << 3;
        const f32x4 w0 = *reinterpret_cast<const f32x4*>(&W2[row * DHID + cc]);
        const f32x4 w1 = *reinterpret_cast<const f32x4*>(&W2[row * DHID + cc + 4]);
        u16x8 wv;
#pragma unroll
        for (int q = 0; q < 4; ++q) { wv[q] = f2bf(w0[q]); wv[4 + q] = f2bf(w1[q]); }
        *reinterpret_cast<u16x8*>(&w2s[row * W2_PAD + cc]) = wv;
    }
    __syncthreads();

    const int lane = tid & 63;
    const int wave = tid >> 6;
    const int quad = lane >> 4;
    const int l15 = lane & 15;
    const int j0 = (jb << 6) + (wave << 4);

    const float* pbrow = pb + (((b << 8) + (j0 + l15)) << 8);

    f32x4 acc[4];
#pragma unroll
    for (int eb = 0; eb < 4; ++eb) acc[eb] = (f32x4){0.f, 0.f, 0.f, 0.f};

#pragma unroll
    for (int k0 = 0; k0 < DHID; k0 += 32) {
        const int g = k0 + (quad << 3);
        const f32x4 p0 = *reinterpret_cast<const f32x4*>(pbrow + g);
        const f32x4 p1 = *reinterpret_cast<const f32x4*>(pbrow + g + 4);
        const f32x4 q0 = *reinterpret_cast<const f32x4*>(&pab1[g]);
        const f32x4 q1 = *reinterpret_cast<const f32x4*>(&pab1[g + 4]);

        s16x8 a;
#pragma unroll
        for (int jj = 0; jj < 4; ++jj) {
            const float z = q0[jj] + p0[jj];
            const float e = __expf(-z);
            const float s = __builtin_amdgcn_rcpf(1.0f + e);
            a[jj] = (short)f2bf(z * s);
        }
#pragma unroll
        for (int jj = 0; jj < 4; ++jj) {
            const float z = q1[jj] + p1[jj];
            const float e = __expf(-z);
            const float s = __builtin_amdgcn_rcpf(1.0f + e);
            a[4 + jj] = (short)f2bf(z * s);
        }

#pragma unroll
        for (int eb = 0; eb < 4; ++eb) {
            const s16x8 bfrag = *reinterpret_cast<const s16x8*>(
                &w2s[(eb * 16 + l15) * W2_PAD + (unsigned)g]);
            acc[eb] = __builtin_amdgcn_mfma_f32_16x16x32_bf16(a, bfrag, acc[eb], 0, 0, 0);
        }
    }

    // epilogue: + b2, store FP32
    const int obase = (((((b << 8) + i) << 8) + j0 + (quad << 2)) << 6) + l15;
#pragma unroll
    for (int eb = 0; eb < 4; ++eb) {
        const float b2v = b2[eb * 16 + l15];
#pragma unroll
        for (int r = 0; r < 4; ++r)
            out[obase + (r << 6) + (eb << 4)] = acc[eb][r] + b2v;
    }
}

extern "C" void kernel_launch(void* const* d_in, const int* in_sizes, int n_in,
                              void* d_out, int out_size, void* d_ws, size_t ws_size,
                              hipStream_t stream) {
    // Inputs proven fp32 (R1 NaN + R4 on-device detector bit-neutral).
    // Map by element count (unique sizes except b_in/b1 which keep dict order).
    const float* x = 0; const float* Win = 0; const float* bin = 0;
    const float* W1 = 0; const float* b1 = 0; const float* W2 = 0; const float* b2 = 0;
    for (int idx = 0; idx < n_in; ++idx) {
        const int s = in_sizes[idx];
        if (s == 262144) x = (const float*)d_in[idx];
        else if (s == 131072) W1 = (const float*)d_in[idx];
        else if (s == 65536) Win = (const float*)d_in[idx];
        else if (s == 16384) W2 = (const float*)d_in[idx];
        else if (s == 64) b2 = (const float*)d_in[idx];
        else if (s == 256) { if (!bin) bin = (const float*)d_in[idx]; else b1 = (const float*)d_in[idx]; }
    }

    float* h  = (float*)d_ws;            // 262144 fp32 = 1 MB
    float* pa = h + 262144;              // 1 MB
    float* pb = pa + 262144;             // 1 MB

    hipLaunchKernelGGL(k_h,   dim3(256),       dim3(256), 0, stream, x, Win, bin, h);
    hipLaunchKernelGGL(k_pab, dim3(256),       dim3(256), 0, stream, h, W1, pa, pb);
    hipLaunchKernelGGL(k_out, dim3(4, 256, 4), dim3(256), 0, stream, pa, pb, b1, W2, b2, (float*)d_out);
}

// Round 10
// 149.432 us; speedup vs baseline: 1.0077x; 1.0077x over previous
//
#include <hip/hip_runtime.h>

#define DIN 256
#define DHID 256
#define DEDGE 64
#define GS 68       // fp32 LDS tile row stride (dwords): 272 B, 16B-aligned, conflict-free
#define W2_PAD 264  // bf16 LDS row stride for W2: 528 B

typedef float f32x4 __attribute__((ext_vector_type(4)));
typedef short s16x8 __attribute__((ext_vector_type(8)));
typedef unsigned int u32x4 __attribute__((ext_vector_type(4)));

__device__ __forceinline__ unsigned short f2bf(float f) {
    unsigned int u = __builtin_bit_cast(unsigned int, f);
    u += 0x7fffu + ((u >> 16) & 1u);   // RNE (values finite here)
    return (unsigned short)(u >> 16);
}
__device__ __forceinline__ unsigned int pk_bf16(float a, float b) {
    return (unsigned int)f2bf(a) | ((unsigned int)f2bf(b) << 16);
}

// -------- Kernel 1: h[m][n] = x[m,:] . Win[n,:]  (bias deferred to k_pab) ---
// grid (16 mt, 4 nt) = 64 blocks. Tile 64x64, thread 4x4, K looped in 64-chunks.
__global__ __launch_bounds__(256) void k_xh(
    const float* __restrict__ x, const float* __restrict__ Win,
    float* __restrict__ h)
{
    __shared__ float as[64 * GS];
    __shared__ float ws[64 * GS];
    const int m0 = blockIdx.x << 6, n0 = blockIdx.y << 6;
    const int tid = threadIdx.x;
    const int rr = tid >> 4;          // 0..15
    const int kk = (tid & 15) << 2;   // 0..60
    const int tx = tid & 15, ty = tid >> 4;

    float acc[4][4] = {};
    for (int kt = 0; kt < 4; ++kt) {
        const int k0 = kt << 6;
        if (kt) __syncthreads();
#pragma unroll
        for (int it = 0; it < 4; ++it) {
            const int row = rr + (it << 4);
            *reinterpret_cast<f32x4*>(&as[row * GS + kk]) =
                *reinterpret_cast<const f32x4*>(&x[(m0 + row) * DIN + k0 + kk]);
            *reinterpret_cast<f32x4*>(&ws[row * GS + kk]) =
                *reinterpret_cast<const f32x4*>(&Win[(n0 + row) * DIN + k0 + kk]);
        }
        __syncthreads();

        for (int k = 0; k < 64; k += 4) {
            f32x4 av[4], wv[4];
#pragma unroll
            for (int r = 0; r < 4; ++r)
                av[r] = *reinterpret_cast<const f32x4*>(&as[(ty + (r << 4)) * GS + k]);
#pragma unroll
            for (int c = 0; c < 4; ++c)
                wv[c] = *reinterpret_cast<const f32x4*>(&ws[(tx + (c << 4)) * GS + k]);
#pragma unroll
            for (int r = 0; r < 4; ++r)
#pragma unroll
                for (int c = 0; c < 4; ++c)
                    acc[r][c] += av[r][0]*wv[c][0] + av[r][1]*wv[c][1]
                               + av[r][2]*wv[c][2] + av[r][3]*wv[c][3];
        }
    }
#pragma unroll
    for (int r = 0; r < 4; ++r)
#pragma unroll
        for (int c = 0; c < 4; ++c)
            h[(m0 + ty + (r << 4)) * DHID + n0 + tx + (c << 4)] = acc[r][c];
}

// -------- Kernel 2: pa/pb[m][g] = (h[m,:]+b_in) . W1[g, half*256:...] -------
// grid (16 mt, 8 = 4nt*2half) = 128 blocks. b_in folded into A-staging.
__global__ __launch_bounds__(256) void k_pab(
    const float* __restrict__ h, const float* __restrict__ W1,
    const float* __restrict__ bin, float* __restrict__ pa, float* __restrict__ pb)
{
    __shared__ float as[64 * GS];
    __shared__ float ws[64 * GS];
    const int m0 = blockIdx.x << 6;
    const int half = blockIdx.y >> 2;
    const int n0 = (blockIdx.y & 3) << 6;
    const int tid = threadIdx.x;
    const int rr = tid >> 4, kk = (tid & 15) << 2;
    const int tx = tid & 15, ty = tid >> 4;

    float acc[4][4] = {};
    for (int kt = 0; kt < 4; ++kt) {
        const int k0 = kt << 6;
        if (kt) __syncthreads();
#pragma unroll
        for (int it = 0; it < 4; ++it) {
            const int row = rr + (it << 4);
            f32x4 av = *reinterpret_cast<const f32x4*>(&h[(m0 + row) * DHID + k0 + kk]);
            av += *reinterpret_cast<const f32x4*>(&bin[k0 + kk]);
            *reinterpret_cast<f32x4*>(&as[row * GS + kk]) = av;
            *reinterpret_cast<f32x4*>(&ws[row * GS + kk]) =
                *reinterpret_cast<const f32x4*>(&W1[(n0 + row) * 512 + (half << 8) + k0 + kk]);
        }
        __syncthreads();

        for (int k = 0; k < 64; k += 4) {
            f32x4 av[4], wv[4];
#pragma unroll
            for (int r = 0; r < 4; ++r)
                av[r] = *reinterpret_cast<const f32x4*>(&as[(ty + (r << 4)) * GS + k]);
#pragma unroll
            for (int c = 0; c < 4; ++c)
                wv[c] = *reinterpret_cast<const f32x4*>(&ws[(tx + (c << 4)) * GS + k]);
#pragma unroll
            for (int r = 0; r < 4; ++r)
#pragma unroll
                for (int c = 0; c < 4; ++c)
                    acc[r][c] += av[r][0]*wv[c][0] + av[r][1]*wv[c][1]
                               + av[r][2]*wv[c][2] + av[r][3]*wv[c][3];
        }
    }
    float* dst = half ? pb : pa;
#pragma unroll
    for (int r = 0; r < 4; ++r)
#pragma unroll
        for (int c = 0; c < 4; ++c)
            dst[(m0 + ty + (r << 4)) * DHID + n0 + tx + (c << 4)] = acc[r][c];
}

// -------- Kernel 3: fused z=silu(pa_i+pb_j+b1); out = z@W2^T + b2 (MFMA) ----
// grid (4 jb, 64 i/4, 4 b), 256 thr = 4 waves; wave: 16 j x 64 e, 4 i at once.
// A[m=l15][k=quad*8+idx] (m->j), B[k][n=l15] (n->e), C/D: col=l15, row=quad*4+reg.
// NOTE: no min-waves bound — let the allocator pick VGPRs freely (64-reg acc).
__global__ __launch_bounds__(256) void k_out(
    const float* __restrict__ pa, const float* __restrict__ pb,
    const float* __restrict__ b1, const float* __restrict__ W2,
    const float* __restrict__ b2, float* __restrict__ out)
{
    __shared__ unsigned short w2s[DEDGE * W2_PAD];   // 33.8 KB
    __shared__ float pab1[4][DHID];                  // 4 KB

    const int jb = blockIdx.x, i0 = blockIdx.y << 2, b = blockIdx.z;
    const int tid = threadIdx.x;

    {
        const float b1v = b1[tid];
#pragma unroll
        for (int ii = 0; ii < 4; ++ii)
            pab1[ii][tid] = pa[(((b << 8) + i0 + ii) << 8) + tid] + b1v;
    }
#pragma unroll
    for (int it = 0; it < 8; ++it) {
        const int t = tid + (it << 8);
        const int row = t >> 5;
        const int cc = (t & 31) << 3;
        const f32x4 w0 = *reinterpret_cast<const f32x4*>(&W2[row * DHID + cc]);
        const f32x4 w1 = *reinterpret_cast<const f32x4*>(&W2[row * DHID + cc + 4]);
        u32x4 wp;
        wp[0] = pk_bf16(w0[0], w0[1]); wp[1] = pk_bf16(w0[2], w0[3]);
        wp[2] = pk_bf16(w1[0], w1[1]); wp[3] = pk_bf16(w1[2], w1[3]);
        *reinterpret_cast<u32x4*>(&w2s[row * W2_PAD + cc]) = wp;
    }
    __syncthreads();

    const int lane = tid & 63, wave = tid >> 6, quad = lane >> 4, l15 = lane & 15;
    const int j0 = (jb << 6) + (wave << 4);
    const float* pbrow = pb + (((b << 8) + (j0 + l15)) << 8);

    f32x4 acc[4][4];   // [ii][eb]
#pragma unroll
    for (int ii = 0; ii < 4; ++ii)
#pragma unroll
        for (int eb = 0; eb < 4; ++eb) acc[ii][eb] = (f32x4){0.f, 0.f, 0.f, 0.f};

    float b2v[4];
#pragma unroll
    for (int eb = 0; eb < 4; ++eb) b2v[eb] = b2[(eb << 4) + l15];

    for (int k0 = 0; k0 < 8; ++k0) {
        const int g = (k0 << 5) + (quad << 3);
        const f32x4 p0 = *reinterpret_cast<const f32x4*>(pbrow + g);
        const f32x4 p1 = *reinterpret_cast<const f32x4*>(pbrow + g + 4);

        s16x8 bfrag[4];
#pragma unroll
        for (int eb = 0; eb < 4; ++eb)
            bfrag[eb] = *reinterpret_cast<const s16x8*>(&w2s[((eb << 4) + l15) * W2_PAD + g]);

#pragma unroll
        for (int ii = 0; ii < 4; ++ii) {
            const f32x4 q0 = *reinterpret_cast<const f32x4*>(&pab1[ii][g]);
            const f32x4 q1 = *reinterpret_cast<const f32x4*>(&pab1[ii][g + 4]);
            float s[8];
#pragma unroll
            for (int jj = 0; jj < 4; ++jj) {
                const float z0 = q0[jj] + p0[jj];
                const float z1 = q1[jj] + p1[jj];
                const float e0 = __expf(-z0);
                const float e1 = __expf(-z1);
                s[jj]     = z0 * __builtin_amdgcn_rcpf(1.0f + e0);
                s[4 + jj] = z1 * __builtin_amdgcn_rcpf(1.0f + e1);
            }
            u32x4 ap;
            ap[0] = pk_bf16(s[0], s[1]); ap[1] = pk_bf16(s[2], s[3]);
            ap[2] = pk_bf16(s[4], s[5]); ap[3] = pk_bf16(s[6], s[7]);
            const s16x8 a = __builtin_bit_cast(s16x8, ap);
#pragma unroll
            for (int eb = 0; eb < 4; ++eb)
                acc[ii][eb] = __builtin_amdgcn_mfma_f32_16x16x32_bf16(a, bfrag[eb], acc[ii][eb], 0, 0, 0);
        }
    }

#pragma unroll
    for (int ii = 0; ii < 4; ++ii) {
        const int obase = (((((b << 8) + i0 + ii) << 8) + j0 + (quad << 2)) << 6) + l15;
#pragma unroll
        for (int eb = 0; eb < 4; ++eb) {
#pragma unroll
            for (int r = 0; r < 4; ++r)
                out[obase + (r << 6) + (eb << 4)] = acc[ii][eb][r] + b2v[eb];
        }
    }
}

extern "C" void kernel_launch(void* const* d_in, const int* in_sizes, int n_in,
                              void* d_out, int out_size, void* d_ws, size_t ws_size,
                              hipStream_t stream) {
    const float* x = 0; const float* Win = 0; const float* bin = 0;
    const float* W1 = 0; const float* b1 = 0; const float* W2 = 0; const float* b2 = 0;
    for (int idx = 0; idx < n_in; ++idx) {
        const int s = in_sizes[idx];
        if (s == 262144) x = (const float*)d_in[idx];
        else if (s == 131072) W1 = (const float*)d_in[idx];
        else if (s == 65536) Win = (const float*)d_in[idx];
        else if (s == 16384) W2 = (const float*)d_in[idx];
        else if (s == 64) b2 = (const float*)d_in[idx];
        else if (s == 256) { if (!bin) bin = (const float*)d_in[idx]; else b1 = (const float*)d_in[idx]; }
    }

    // R5-proven 3 MB workspace layout.
    float* h  = (float*)d_ws;            // 1 MB
    float* pa = h + 262144;              // 1 MB
    float* pb = pa + 262144;             // 1 MB

    hipLaunchKernelGGL(k_xh,  dim3(16, 4),    dim3(256), 0, stream, x, Win, h);
    hipLaunchKernelGGL(k_pab, dim3(16, 8),    dim3(256), 0, stream, h, W1, bin, pa, pb);
    hipLaunchKernelGGL(k_out, dim3(4, 64, 4), dim3(256), 0, stream, pa, pb, b1, W2, b2, (float*)d_out);
}

// Round 11
// 130.149 us; speedup vs baseline: 1.1570x; 1.1482x over previous
//
#include <hip/hip_runtime.h>

#define DIN 256
#define DHID 256
#define DEDGE 64
#define GS 68       // fp32 LDS tile row stride (dwords): 272 B, 16B-aligned, conflict-free
#define W2_PAD 264  // bf16 LDS row stride for W2: 528 B

typedef float f32x4 __attribute__((ext_vector_type(4)));
typedef short s16x8 __attribute__((ext_vector_type(8)));
typedef unsigned int u32x4 __attribute__((ext_vector_type(4)));

__device__ __forceinline__ unsigned short f2bf(float f) {
    unsigned int u = __builtin_bit_cast(unsigned int, f);
    u += 0x7fffu + ((u >> 16) & 1u);   // RNE (values finite here)
    return (unsigned short)(u >> 16);
}
__device__ __forceinline__ unsigned int pk_bf16(float a, float b) {
    return (unsigned int)f2bf(a) | ((unsigned int)f2bf(b) << 16);
}

// -------- Kernel 1: hp[kc][m][n] = sum_{k in 64-chunk kc} x[m][k] * Win[n][k]
// grid (16 mt, 4 nt, 4 kc) = 256 blocks. Tile 64x64, thread 4x4, K-chunk 64.
__global__ __launch_bounds__(256) void k_xh(
    const float* __restrict__ x, const float* __restrict__ Win,
    float* __restrict__ hp)
{
    __shared__ float as[64 * GS];
    __shared__ float ws[64 * GS];
    const int m0 = blockIdx.x << 6, n0 = blockIdx.y << 6, k0 = blockIdx.z << 6;
    const int tid = threadIdx.x;
    const int rr = tid >> 4;          // 0..15
    const int kk = (tid & 15) << 2;   // 0..60

#pragma unroll
    for (int it = 0; it < 4; ++it) {
        const int row = rr + (it << 4);
        *reinterpret_cast<f32x4*>(&as[row * GS + kk]) =
            *reinterpret_cast<const f32x4*>(&x[(m0 + row) * DIN + k0 + kk]);
        *reinterpret_cast<f32x4*>(&ws[row * GS + kk]) =
            *reinterpret_cast<const f32x4*>(&Win[(n0 + row) * DIN + k0 + kk]);
    }
    __syncthreads();

    const int tx = tid & 15, ty = tid >> 4;
    float acc[4][4] = {};
    for (int k = 0; k < 64; k += 4) {
        f32x4 av[4], wv[4];
#pragma unroll
        for (int r = 0; r < 4; ++r)
            av[r] = *reinterpret_cast<const f32x4*>(&as[(ty + (r << 4)) * GS + k]);
#pragma unroll
        for (int c = 0; c < 4; ++c)
            wv[c] = *reinterpret_cast<const f32x4*>(&ws[(tx + (c << 4)) * GS + k]);
#pragma unroll
        for (int r = 0; r < 4; ++r)
#pragma unroll
            for (int c = 0; c < 4; ++c)
                acc[r][c] += av[r][0]*wv[c][0] + av[r][1]*wv[c][1]
                           + av[r][2]*wv[c][2] + av[r][3]*wv[c][3];
    }
    float* dst = hp + ((size_t)blockIdx.z << 18);
#pragma unroll
    for (int r = 0; r < 4; ++r)
#pragma unroll
        for (int c = 0; c < 4; ++c)
            dst[(m0 + ty + (r << 4)) * DHID + n0 + tx + (c << 4)] = acc[r][c];
}

// -------- Kernel 2: pap/pbp[kc][m][g] = sum_{d in 128-chunk} h[m][d]*W1[g][half*256+d]
// h = hp0+hp1+hp2+hp3+b_in folded into A-staging. grid (16 mt, 8 = 4nt*2half, 2 kc) = 256.
__global__ __launch_bounds__(256) void k_pab(
    const float* __restrict__ hp, const float* __restrict__ W1,
    const float* __restrict__ bin, float* __restrict__ pap, float* __restrict__ pbp)
{
    __shared__ float as[64 * GS];
    __shared__ float ws[64 * GS];
    const int m0 = blockIdx.x << 6;
    const int half = blockIdx.y >> 2;
    const int n0 = (blockIdx.y & 3) << 6;
    const int kc = blockIdx.z;
    const int tid = threadIdx.x;
    const int rr = tid >> 4, kk = (tid & 15) << 2;
    const int tx = tid & 15, ty = tid >> 4;

    float acc[4][4] = {};
    for (int kt = 0; kt < 2; ++kt) {
        const int k0 = (kc << 7) + (kt << 6);
        if (kt) __syncthreads();
#pragma unroll
        for (int it = 0; it < 4; ++it) {
            const int row = rr + (it << 4);
            const int aoff = (m0 + row) * DHID + k0 + kk;
            f32x4 av = *reinterpret_cast<const f32x4*>(&hp[aoff]);
            av += *reinterpret_cast<const f32x4*>(&hp[aoff + (1 << 18)]);
            av += *reinterpret_cast<const f32x4*>(&hp[aoff + (2 << 18)]);
            av += *reinterpret_cast<const f32x4*>(&hp[aoff + (3 << 18)]);
            av += *reinterpret_cast<const f32x4*>(&bin[k0 + kk]);
            *reinterpret_cast<f32x4*>(&as[row * GS + kk]) = av;
            *reinterpret_cast<f32x4*>(&ws[row * GS + kk]) =
                *reinterpret_cast<const f32x4*>(&W1[(n0 + row) * 512 + (half << 8) + k0 + kk]);
        }
        __syncthreads();

        for (int k = 0; k < 64; k += 4) {
            f32x4 av[4], wv[4];
#pragma unroll
            for (int r = 0; r < 4; ++r)
                av[r] = *reinterpret_cast<const f32x4*>(&as[(ty + (r << 4)) * GS + k]);
#pragma unroll
            for (int c = 0; c < 4; ++c)
                wv[c] = *reinterpret_cast<const f32x4*>(&ws[(tx + (c << 4)) * GS + k]);
#pragma unroll
            for (int r = 0; r < 4; ++r)
#pragma unroll
                for (int c = 0; c < 4; ++c)
                    acc[r][c] += av[r][0]*wv[c][0] + av[r][1]*wv[c][1]
                               + av[r][2]*wv[c][2] + av[r][3]*wv[c][3];
        }
    }
    float* dst = (half ? pbp : pap) + ((size_t)kc << 18);
#pragma unroll
    for (int r = 0; r < 4; ++r)
#pragma unroll
        for (int c = 0; c < 4; ++c)
            dst[(m0 + ty + (r << 4)) * DHID + n0 + tx + (c << 4)] = acc[r][c];
}

// -------- Kernel 3: fused z=silu(pa_i+pb_j+b1); out = z@W2^T + b2 (MFMA) ----
// grid (4 jb, 64 i/4, 4 b), 256 thr = 4 waves; wave: 16 j x 64 e, 4 i at once.
// pa = pap0+pap1 (+b1) folded in staging; pb = pbp0+pbp1 summed at load.
// A[m=l15][k=quad*8+idx] (m->j), B[k][n=l15] (n->e), C/D: col=l15, row=quad*4+reg.
__global__ __launch_bounds__(256) void k_out(
    const float* __restrict__ pap, const float* __restrict__ pbp,
    const float* __restrict__ b1, const float* __restrict__ W2,
    const float* __restrict__ b2, float* __restrict__ out)
{
    __shared__ unsigned short w2s[DEDGE * W2_PAD];   // 33.8 KB
    __shared__ float pab1[4][DHID];                  // 4 KB

    const int jb = blockIdx.x, i0 = blockIdx.y << 2, b = blockIdx.z;
    const int tid = threadIdx.x;

    {
        const float b1v = b1[tid];
#pragma unroll
        for (int ii = 0; ii < 4; ++ii) {
            const int off = (((b << 8) + i0 + ii) << 8) + tid;
            pab1[ii][tid] = pap[off] + pap[off + (1 << 18)] + b1v;
        }
    }
#pragma unroll
    for (int it = 0; it < 8; ++it) {
        const int t = tid + (it << 8);
        const int row = t >> 5;
        const int cc = (t & 31) << 3;
        const f32x4 w0 = *reinterpret_cast<const f32x4*>(&W2[row * DHID + cc]);
        const f32x4 w1 = *reinterpret_cast<const f32x4*>(&W2[row * DHID + cc + 4]);
        u32x4 wp;
        wp[0] = pk_bf16(w0[0], w0[1]); wp[1] = pk_bf16(w0[2], w0[3]);
        wp[2] = pk_bf16(w1[0], w1[1]); wp[3] = pk_bf16(w1[2], w1[3]);
        *reinterpret_cast<u32x4*>(&w2s[row * W2_PAD + cc]) = wp;
    }
    __syncthreads();

    const int lane = tid & 63, wave = tid >> 6, quad = lane >> 4, l15 = lane & 15;
    const int j0 = (jb << 6) + (wave << 4);
    const int pboff = (((b << 8) + (j0 + l15)) << 8);
    const float* pbq0 = pbp + pboff;
    const float* pbq1 = pbp + (1 << 18) + pboff;

    f32x4 acc[4][4];   // [ii][eb]
#pragma unroll
    for (int ii = 0; ii < 4; ++ii)
#pragma unroll
        for (int eb = 0; eb < 4; ++eb) acc[ii][eb] = (f32x4){0.f, 0.f, 0.f, 0.f};

    float b2v[4];
#pragma unroll
    for (int eb = 0; eb < 4; ++eb) b2v[eb] = b2[(eb << 4) + l15];

    for (int k0 = 0; k0 < 8; ++k0) {
        const int g = (k0 << 5) + (quad << 3);
        const f32x4 p0 = *reinterpret_cast<const f32x4*>(pbq0 + g)
                       + *reinterpret_cast<const f32x4*>(pbq1 + g);
        const f32x4 p1 = *reinterpret_cast<const f32x4*>(pbq0 + g + 4)
                       + *reinterpret_cast<const f32x4*>(pbq1 + g + 4);

        s16x8 bfrag[4];
#pragma unroll
        for (int eb = 0; eb < 4; ++eb)
            bfrag[eb] = *reinterpret_cast<const s16x8*>(&w2s[((eb << 4) + l15) * W2_PAD + g]);

#pragma unroll
        for (int ii = 0; ii < 4; ++ii) {
            const f32x4 q0 = *reinterpret_cast<const f32x4*>(&pab1[ii][g]);
            const f32x4 q1 = *reinterpret_cast<const f32x4*>(&pab1[ii][g + 4]);
            float s[8];
#pragma unroll
            for (int jj = 0; jj < 4; ++jj) {
                const float z0 = q0[jj] + p0[jj];
                const float z1 = q1[jj] + p1[jj];
                const float e0 = __expf(-z0);
                const float e1 = __expf(-z1);
                s[jj]     = z0 * __builtin_amdgcn_rcpf(1.0f + e0);
                s[4 + jj] = z1 * __builtin_amdgcn_rcpf(1.0f + e1);
            }
            u32x4 ap;
            ap[0] = pk_bf16(s[0], s[1]); ap[1] = pk_bf16(s[2], s[3]);
            ap[2] = pk_bf16(s[4], s[5]); ap[3] = pk_bf16(s[6], s[7]);
            const s16x8 a = __builtin_bit_cast(s16x8, ap);
#pragma unroll
            for (int eb = 0; eb < 4; ++eb)
                acc[ii][eb] = __builtin_amdgcn_mfma_f32_16x16x32_bf16(a, bfrag[eb], acc[ii][eb], 0, 0, 0);
        }
    }

#pragma unroll
    for (int ii = 0; ii < 4; ++ii) {
        const int obase = (((((b << 8) + i0 + ii) << 8) + j0 + (quad << 2)) << 6) + l15;
#pragma unroll
        for (int eb = 0; eb < 4; ++eb) {
#pragma unroll
            for (int r = 0; r < 4; ++r)
                out[obase + (r << 6) + (eb << 4)] = acc[ii][eb][r] + b2v[eb];
        }
    }
}

extern "C" void kernel_launch(void* const* d_in, const int* in_sizes, int n_in,
                              void* d_out, int out_size, void* d_ws, size_t ws_size,
                              hipStream_t stream) {
    const float* x = 0; const float* Win = 0; const float* bin = 0;
    const float* W1 = 0; const float* b1 = 0; const float* W2 = 0; const float* b2 = 0;
    for (int idx = 0; idx < n_in; ++idx) {
        const int s = in_sizes[idx];
        if (s == 262144) x = (const float*)d_in[idx];
        else if (s == 131072) W1 = (const float*)d_in[idx];
        else if (s == 65536) Win = (const float*)d_in[idx];
        else if (s == 16384) W2 = (const float*)d_in[idx];
        else if (s == 64) b2 = (const float*)d_in[idx];
        else if (s == 256) { if (!bin) bin = (const float*)d_in[idx]; else b1 = (const float*)d_in[idx]; }
    }

    // ws_size = 256 MiB (measured via harness poison WRITE_SIZE in R10); 8 MB used.
    float* ws = (float*)d_ws;
    float* hp  = ws;                        // 4 x 262144 = 4 MB (K-split partials)
    float* pap = hp + (4 << 18);            // 2 x 262144 = 2 MB
    float* pbp = pap + (2 << 18);           // 2 x 262144 = 2 MB

    hipLaunchKernelGGL(k_xh,  dim3(16, 4, 4), dim3(256), 0, stream, x, Win, hp);
    hipLaunchKernelGGL(k_pab, dim3(16, 8, 2), dim3(256), 0, stream, hp, W1, bin, pap, pbp);
    hipLaunchKernelGGL(k_out, dim3(4, 64, 4), dim3(256), 0, stream, pap, pbp, b1, W2, b2, (float*)d_out);
}